// Round 2
// baseline (812.306 us; speedup 1.0000x reference)
//
#include <hip/hip_runtime.h>

// Spatially varying anisotropic 2D elastic wave sim, 384x384, 192 steps.
// Round 10: persistent single-launch kernel, R8 inner math unchanged.
//  - R9 failure root-caused to exchange-buffer pointers derived from a
//    const __restrict__ param (readonly/noalias UB -> stale halo reads)
//    and/or cooperative-launch machinery under graph capture.
//  - Fix: exchange sets + barrier counters are SEPARATE plain params;
//    manual grid barrier (device-scope atomics + __threadfence, one
//    counter slot per boundary, zeroed by setup each launch); plain
//    <<<>>> launch. Co-residency guaranteed: 256 blocks / 256 CUs,
//    37.6 KiB LDS, >=1 block/CU occupancy -> no deadlock.

typedef float v2f __attribute__((ext_vector_type(2)));

#define NXg 384
#define NYg 384
#define NPT (NXg * NYg)
#define NFRAMES 48

#define OWN 24
#define HALO 12
#define TS 48
#define KSTEPS 12
#define NPHASE 16
#define NBLK 256

#define H_   1e-4
#define DT_  5e-9
#define RHO_ 1610.0

#define B11_LO 5e10f
#define B11_HI 2.5e11f
#define B22_LO 5e9f
#define B22_HI 5e10f
#define B12_LO 5e9f
#define B12_HI 5e10f
#define B16_LO 0.0f
#define B16_HI 6e10f
#define B26_LO 0.0f
#define B26_HI 2e10f
#define B66_LO 5e9f
#define B66_HI 3e10f

static __device__ __constant__ float kScale  = (float)(DT_ * DT_ / (H_ * H_) / RHO_);
static __device__ __constant__ float kSrcScl = (float)(DT_ * DT_ / RHO_);

__device__ __forceinline__ float clipf(float v, float lo, float hi) {
    return fminf(fmaxf(v, lo), hi);
}
__device__ __forceinline__ v2f vfma(v2f a, v2f b, v2f c) {
    return __builtin_elementwise_fma(a, b, c);
}
__device__ __forceinline__ v2f vbc(float s) { v2f r; r[0] = s; r[1] = s; return r; }
__device__ __forceinline__ v2f vswap(v2f a) { return __builtin_shufflevector(a, a, 1, 0); }

// barrier that only waits LDS (no vmcnt drain); memory clobber pins ordering
#define LDS_BARRIER() asm volatile("s_waitcnt lgkmcnt(0)\n\ts_barrier" ::: "memory")

// Manual grid barrier: one fresh counter slot per use (no sense reversal).
// __syncthreads drains this block's stores (vmcnt0); thread 0's
// __threadfence (agent acq_rel) writes back this XCD's L2 before the
// arrival add, and invalidates stale lines after the spin completes.
__device__ __forceinline__ void grid_barrier(unsigned* cnt) {
    __syncthreads();
    if (threadIdx.x == 0) {
        __threadfence();
        __hip_atomic_fetch_add(cnt, 1u, __ATOMIC_ACQ_REL, __HIP_MEMORY_SCOPE_AGENT);
        while (__hip_atomic_load(cnt, __ATOMIC_RELAXED, __HIP_MEMORY_SCOPE_AGENT) < NBLK) {
            __builtin_amdgcn_s_sleep(2);
        }
        __threadfence();
    }
    __syncthreads();
}

// ws float layout:
// [0..4NPT):    C0 = float4{A11, A22, A12p66, A16}  (pre-scaled)
// [4NPT..8NPT): C1 = float4{A26, A66, GS, 0}
// [8NPT..12NPT):  exchange set0: float4{cur.x, cur.y, old.x, old.y}
// [12NPT..16NPT): exchange set1
// [16NPT..16NPT+16): barrier counters (uint), zeroed by setup each launch

__global__ __launch_bounds__(256)
void setup_kernel(const float* __restrict__ lc11, const float* __restrict__ lc12,
                  const float* __restrict__ lc16, const float* __restrict__ lc22,
                  const float* __restrict__ lc26, const float* __restrict__ lc66,
                  const float* __restrict__ gauss, float* __restrict__ ws,
                  unsigned* __restrict__ bar) {
    int i = blockIdx.x * blockDim.x + threadIdx.x;
    if (i < 16) bar[i] = 0u;
    if (i >= NPT) return;
    float C11 = clipf(expf(lc11[i]), B11_LO, B11_HI);
    float C12 = clipf(expf(lc12[i]), B12_LO, B12_HI);
    float C16 = clipf(expf(lc16[i]), B16_LO, B16_HI);
    float C22 = clipf(expf(lc22[i]), B22_LO, B22_HI);
    float C26 = clipf(expf(lc26[i]), B26_LO, B26_HI);
    float C66 = clipf(expf(lc66[i]), B66_LO, B66_HI);
    float s = kScale;
    float4* C0 = (float4*)ws;
    float4* C1 = (float4*)(ws + 4 * (size_t)NPT);
    C0[i] = make_float4(C11 * s, C22 * s, (C12 + C66) * s, C16 * s);
    C1[i] = make_float4(C26 * s, C66 * s, gauss[i] * kSrcScl, 0.0f);
}

__global__ __launch_bounds__(256, 1)
void fused_persistent(const float4* __restrict__ C0, const float4* __restrict__ C1,
                      const float* __restrict__ sig,
                      float4* xset0, float4* xset1, unsigned* bar,
                      float* __restrict__ out) {
    __shared__ v2f sb[2][TS][TS + 1];

    const int tid = threadIdx.x;
    const int tx = tid >> 4;
    const int ty = tid & 15;
    const int r0 = 3 * tx;
    const int c0 = 3 * ty;
    const int gx0 = blockIdx.y * OWN - HALO;
    const int gy0 = blockIdx.x * OWN - HALO;

    v2f cur[9], old_[9];
    v2f ca[9], cb[9];                       // {A11,A66}, {A66,A22}
    float a12p66[9], a16[9], a26[9], gs[9];
    int gidx[9];
    int dmask = 0;

    // coeff load happens ONCE for the whole 192-step run; state starts at 0
#pragma unroll
    for (int i = 0; i < 3; ++i) {
#pragma unroll
        for (int j = 0; j < 3; ++j) {
            int p = i * 3 + j;
            int gx = gx0 + r0 + i;
            int gy = gy0 + c0 + j;
            bool d = (unsigned)gx < (unsigned)NXg && (unsigned)gy < (unsigned)NYg;
            int g = d ? gx * NYg + gy : 0;
            gidx[p] = g;
            if (d) dmask |= (1 << p);
            cur[p] = vbc(0.0f); old_[p] = vbc(0.0f);
            float4 k0 = d ? C0[g] : make_float4(0, 0, 0, 0);
            float4 k1 = d ? C1[g] : make_float4(0, 0, 0, 0);
            v2f t; t[0] = k0.x; t[1] = k1.y; ca[p] = t;   // {A11, A66}
            v2f u; u[0] = k1.y; u[1] = k0.y; cb[p] = u;   // {A66, A22}
            a12p66[p] = k0.z; a16[p] = k0.w; a26[p] = k1.x; gs[p] = k1.z;
        }
    }

    // clamped halo coords (trapezoid garbage-tolerance at staging rim)
    const int rm = (r0 > 0) ? r0 - 1 : 0;
    const int rp = (r0 + 3 < TS) ? r0 + 3 : TS - 1;
    const int cm = (c0 > 0) ? c0 - 1 : 0;
    const int cp = (c0 + 3 < TS) ? c0 + 3 : TS - 1;

    const bool owned = (tx >= 4) && (tx < 12) && (ty >= 4) && (ty < 12);

    v2f c20; c20[0] = 2.0f; c20[1] = 0.0f;
    v2f c02; c02[0] = 0.0f; c02[1] = 2.0f;
    const v2f m2 = vbc(-2.0f);
    const v2f qt = vbc(0.25f);
    const v2f two = vbc(2.0f);

#pragma unroll 1
    for (int L = 0; L < NPHASE; ++L) {
        // preload this phase's source values (no s_loads inside the step loop)
        const int t0 = L * KSTEPS;
        float sigv[KSTEPS];
#pragma unroll
        for (int k = 0; k < KSTEPS; ++k) sigv[k] = sig[t0 + k];

        // publish current state into buffer 0 (all threads; owned rewrite
        // the identical values left there by step 12 of the previous phase)
#pragma unroll
        for (int i = 0; i < 3; ++i)
#pragma unroll
            for (int j = 0; j < 3; ++j)
                sb[0][r0 + i][c0 + j] = cur[i * 3 + j];
        LDS_BARRIER();

#pragma unroll 1
        for (int s = 1; s <= KSTEPS; ++s) {
            const v2f (*rb)[TS + 1] = sb[(s - 1) & 1];
            v2f (*wb)[TS + 1] = sb[s & 1];
            v2f vsig; vsig[0] = 0.0f; vsig[1] = sigv[s - 1];

            // assemble 5x5 v2f window: own 3x3 from regs + 16 halo b64 reads
            v2f v[5][5];
#pragma unroll
            for (int i = 0; i < 3; ++i)
#pragma unroll
                for (int j = 0; j < 3; ++j)
                    v[i + 1][j + 1] = cur[i * 3 + j];
            v[0][0] = rb[rm][cm];  v[0][4] = rb[rm][cp];
            v[4][0] = rb[rp][cm];  v[4][4] = rb[rp][cp];
#pragma unroll
            for (int j = 0; j < 3; ++j) {
                v[0][j + 1] = rb[rm][c0 + j];
                v[4][j + 1] = rb[rp][c0 + j];
                v[j + 1][0] = rb[r0 + j][cm];
                v[j + 1][4] = rb[r0 + j][cp];
            }

            // horizontal differences shared across the 9 points' cross-derivs
            v2f dh[5][3];
#pragma unroll
            for (int i = 0; i < 5; ++i)
#pragma unroll
                for (int j = 0; j < 3; ++j)
                    dh[i][j] = v[i][j + 2] - v[i][j];

#pragma unroll
            for (int i = 0; i < 3; ++i)
#pragma unroll
                for (int j = 0; j < 3; ++j) {
                    int p = i * 3 + j;
                    v2f c = v[i + 1][j + 1];
                    v2f sxx = vfma(m2, c, v[i][j + 1] + v[i + 2][j + 1]);  // pk
                    v2f syy = vfma(m2, c, v[i + 1][j] + v[i + 1][j + 2]);  // pk
                    v2f sxy = qt * (dh[i + 2][j] - dh[i][j]);              // pk

                    // t4 = {2*sxy.x + sxx.y, sxx.x}; t5 = {syy.y, 2*sxy.y + syy.x}
                    v2f t4 = vfma(c20, vbc(sxy[0]), vswap(sxx));
                    v2f t5 = vfma(c02, vbc(sxy[1]), vswap(syy));
                    // L = {lux, luy}
                    v2f Lv = ca[p] * sxx;
                    Lv = vfma(cb[p], syy, Lv);
                    Lv = vfma(vbc(a12p66[p]), vswap(sxy), Lv);
                    Lv = vfma(vbc(a16[p]), t4, Lv);
                    Lv = vfma(vbc(a26[p]), t5, Lv);
                    // source on y only: {lux, sig*gs + luy} (exact: 0*gs+lux)
                    Lv = vfma(vsig, vbc(gs[p]), Lv);
                    // n = fma(2, c, L) - old
                    v2f n = vfma(two, c, Lv) - old_[p];
                    old_[p] = c;
                    cur[p] = n;
                }

            // frame output at global t = t0 + s - 1; t%4==3 <=> s%4==0
            // (fire-and-forget: the step barrier does NOT drain vmcnt)
            if ((s & 3) == 0 && owned) {
                int f = 3 * L + (s >> 2) - 1;
                float* oux = out + (size_t)f * NPT;
                float* ouy = out + (size_t)(NFRAMES + f) * NPT;
#pragma unroll
                for (int p = 0; p < 9; ++p) {
                    oux[gidx[p]] = cur[p][0];
                    ouy[gidx[p]] = cur[p][1];
                }
            }

            // publish new values; ONE lgkm-only barrier per step (double buffered)
#pragma unroll
            for (int i = 0; i < 3; ++i)
#pragma unroll
                for (int j = 0; j < 3; ++j)
                    wb[r0 + i][c0 + j] = cur[i * 3 + j];
            LDS_BARRIER();
        }

        // phase boundary: exchange the halo ring through global memory.
        // Double-buffered sets prevent any cross-phase skew race.
        if (L + 1 < NPHASE) {
            float4* xb = (L & 1) ? xset1 : xset0;
            if (owned) {
#pragma unroll
                for (int p = 0; p < 9; ++p)
                    xb[gidx[p]] = make_float4(cur[p][0], cur[p][1],
                                              old_[p][0], old_[p][1]);
            }
            grid_barrier(bar + L);
            if (!owned) {
#pragma unroll
                for (int p = 0; p < 9; ++p) {
                    if ((dmask >> p) & 1) {
                        float4 st = xb[gidx[p]];
                        v2f c; c[0] = st.x; c[1] = st.y;
                        v2f o; o[0] = st.z; o[1] = st.w;
                        cur[p] = c; old_[p] = o;
                    } else {
                        cur[p] = vbc(0.0f); old_[p] = vbc(0.0f);
                    }
                }
            }
        }
    }
}

extern "C" void kernel_launch(void* const* d_in, const int* in_sizes, int n_in,
                              void* d_out, int out_size, void* d_ws, size_t ws_size,
                              hipStream_t stream) {
    const float* lc11  = (const float*)d_in[0];
    const float* lc12  = (const float*)d_in[1];
    const float* lc16  = (const float*)d_in[2];
    const float* lc22  = (const float*)d_in[3];
    const float* lc26  = (const float*)d_in[4];
    const float* lc66  = (const float*)d_in[5];
    const float* gauss = (const float*)d_in[6];
    const float* sigp  = (const float*)d_in[7];

    float* ws  = (float*)d_ws;
    float* out = (float*)d_out;

    const float4* C0    = (const float4*)ws;
    const float4* C1    = (const float4*)(ws + 4 * (size_t)NPT);
    float4*       xset0 = (float4*)(ws + 8 * (size_t)NPT);
    float4*       xset1 = (float4*)(ws + 12 * (size_t)NPT);
    unsigned*     bar   = (unsigned*)(ws + 16 * (size_t)NPT);

    setup_kernel<<<(NPT + 255) / 256, 256, 0, stream>>>(lc11, lc12, lc16, lc22,
                                                        lc26, lc66, gauss, ws, bar);

    dim3 grid(NXg / OWN, NYg / OWN);  // 16x16 = 256 blocks, 1 per CU
    fused_persistent<<<grid, 256, 0, stream>>>(C0, C1, sigp, xset0, xset1, bar, out);
}

// Round 3
// 370.920 us; speedup vs baseline: 2.1900x; 2.1900x over previous
//
#include <hip/hip_runtime.h>

// Spatially varying anisotropic 2D elastic wave sim, 384x384, 192 steps.
// Round 11: back to multi-launch (R8 structure, proven), new geometry for
// latency hiding. R10 diagnosis: VALUBusy 9.4%, HBM 2.5% -> latency-bound
// at 1 block/CU (1 wave/SIMD; per-step ds_read + s_barrier = dead SIMD).
//  - OWN=16, HALO=KSTEPS=8, TS=32, 2x2 points/thread, 256 thr/block
//  - grid 24x24 = 576 blocks -> 2-3 blocks/CU resident (LDS 16.9 KB,
//    __launch_bounds__(256,3) caps VGPR at 170) -> 2-3 waves/SIMD
//  - 24 launches; total cell-steps identical; halo ratio unchanged (4x)
//  - same packed v2f math, wide float4 state/coeffs, lgkm-only barrier

typedef float v2f __attribute__((ext_vector_type(2)));

#define NXg 384
#define NYg 384
#define NPT (NXg * NYg)
#define NFRAMES 48

#define OWN 16
#define HALO 8
#define TS 32
#define KSTEPS 8
#define NLAUNCH 24

#define H_   1e-4
#define DT_  5e-9
#define RHO_ 1610.0

#define B11_LO 5e10f
#define B11_HI 2.5e11f
#define B22_LO 5e9f
#define B22_HI 5e10f
#define B12_LO 5e9f
#define B12_HI 5e10f
#define B16_LO 0.0f
#define B16_HI 6e10f
#define B26_LO 0.0f
#define B26_HI 2e10f
#define B66_LO 5e9f
#define B66_HI 3e10f

static __device__ __constant__ float kScale  = (float)(DT_ * DT_ / (H_ * H_) / RHO_);
static __device__ __constant__ float kSrcScl = (float)(DT_ * DT_ / RHO_);

__device__ __forceinline__ float clipf(float v, float lo, float hi) {
    return fminf(fmaxf(v, lo), hi);
}
__device__ __forceinline__ v2f vfma(v2f a, v2f b, v2f c) {
    return __builtin_elementwise_fma(a, b, c);
}
__device__ __forceinline__ v2f vbc(float s) { v2f r; r[0] = s; r[1] = s; return r; }
__device__ __forceinline__ v2f vswap(v2f a) { return __builtin_shufflevector(a, a, 1, 0); }

// barrier that only waits LDS (no vmcnt drain); memory clobber pins ordering
#define LDS_BARRIER() asm volatile("s_waitcnt lgkmcnt(0)\n\ts_barrier" ::: "memory")

// ws float layout:
// [0..4NPT):    C0 = float4{A11, A22, A12p66, A16}  (pre-scaled)
// [4NPT..8NPT): C1 = float4{A26, A66, GS, 0}
// [8NPT..12NPT):  state set0: float4{cur.x, cur.y, old.x, old.y}
// [12NPT..16NPT): state set1

__global__ __launch_bounds__(256)
void setup_kernel(const float* __restrict__ lc11, const float* __restrict__ lc12,
                  const float* __restrict__ lc16, const float* __restrict__ lc22,
                  const float* __restrict__ lc26, const float* __restrict__ lc66,
                  const float* __restrict__ gauss, float* __restrict__ ws) {
    int i = blockIdx.x * blockDim.x + threadIdx.x;
    if (i >= NPT) return;
    float C11 = clipf(expf(lc11[i]), B11_LO, B11_HI);
    float C12 = clipf(expf(lc12[i]), B12_LO, B12_HI);
    float C16 = clipf(expf(lc16[i]), B16_LO, B16_HI);
    float C22 = clipf(expf(lc22[i]), B22_LO, B22_HI);
    float C26 = clipf(expf(lc26[i]), B26_LO, B26_HI);
    float C66 = clipf(expf(lc66[i]), B66_LO, B66_HI);
    float s = kScale;
    float4* C0 = (float4*)ws;
    float4* C1 = (float4*)(ws + 4 * (size_t)NPT);
    C0[i] = make_float4(C11 * s, C22 * s, (C12 + C66) * s, C16 * s);
    C1[i] = make_float4(C26 * s, C66 * s, gauss[i] * kSrcScl, 0.0f);
    float4* s0 = (float4*)(ws + 8 * (size_t)NPT);
    s0[i] = make_float4(0.0f, 0.0f, 0.0f, 0.0f);
}

__global__ __launch_bounds__(256, 3)
void fused_kernel(const float* __restrict__ ws, const float* __restrict__ sig,
                  const float4* __restrict__ inS, float4* __restrict__ outS,
                  float* __restrict__ out, int L) {
    __shared__ v2f sb[2][TS][TS + 1];

    const int tid = threadIdx.x;
    const int tx = tid >> 4;
    const int ty = tid & 15;
    const int r0 = 2 * tx;
    const int c0 = 2 * ty;
    const int gx0 = blockIdx.y * OWN - HALO;
    const int gy0 = blockIdx.x * OWN - HALO;

    const float4* __restrict__ C0 = (const float4*)ws;
    const float4* __restrict__ C1 = (const float4*)(ws + 4 * (size_t)NPT);

    v2f cur[4], old_[4];
    v2f ca[4], cb[4];                       // {A11,A66}, {A66,A22}
    float a12p66[4], a16[4], a26[4], gs[4];
    int gidx[4];

#pragma unroll
    for (int i = 0; i < 2; ++i) {
#pragma unroll
        for (int j = 0; j < 2; ++j) {
            int p = i * 2 + j;
            int gx = gx0 + r0 + i;
            int gy = gy0 + c0 + j;
            bool d = (unsigned)gx < (unsigned)NXg && (unsigned)gy < (unsigned)NYg;
            int g = d ? gx * NYg + gy : 0;
            gidx[p] = g;
            float4 st = d ? inS[g] : make_float4(0, 0, 0, 0);
            v2f c; c[0] = st.x; c[1] = st.y;
            v2f o; o[0] = st.z; o[1] = st.w;
            cur[p] = c; old_[p] = o;
            float4 k0 = d ? C0[g] : make_float4(0, 0, 0, 0);
            float4 k1 = d ? C1[g] : make_float4(0, 0, 0, 0);
            v2f t; t[0] = k0.x; t[1] = k1.y; ca[p] = t;   // {A11, A66}
            v2f u; u[0] = k1.y; u[1] = k0.y; cb[p] = u;   // {A66, A22}
            a12p66[p] = k0.z; a16[p] = k0.w; a26[p] = k1.x; gs[p] = k1.z;
        }
    }

    // preload all step source values (no s_loads inside the loop)
    const int t0 = L * KSTEPS;
    float sigv[KSTEPS];
#pragma unroll
    for (int k = 0; k < KSTEPS; ++k) sigv[k] = sig[t0 + k];

    // clamped halo coords (trapezoid garbage-tolerance at staging rim)
    const int rm = (r0 > 0) ? r0 - 1 : 0;
    const int rp = (r0 + 2 < TS) ? r0 + 2 : TS - 1;
    const int cm = (c0 > 0) ? c0 - 1 : 0;
    const int cp = (c0 + 2 < TS) ? c0 + 2 : TS - 1;

    const bool owned = (tx >= 4) && (tx < 12) && (ty >= 4) && (ty < 12);

    // publish initial values into buffer 0
#pragma unroll
    for (int i = 0; i < 2; ++i)
#pragma unroll
        for (int j = 0; j < 2; ++j)
            sb[0][r0 + i][c0 + j] = cur[i * 2 + j];
    LDS_BARRIER();

    v2f c20; c20[0] = 2.0f; c20[1] = 0.0f;
    v2f c02; c02[0] = 0.0f; c02[1] = 2.0f;
    const v2f m2 = vbc(-2.0f);
    const v2f qt = vbc(0.25f);
    const v2f two = vbc(2.0f);

#pragma unroll 1
    for (int s = 1; s <= KSTEPS; ++s) {
        const v2f (*rb)[TS + 1] = sb[(s - 1) & 1];
        v2f (*wb)[TS + 1] = sb[s & 1];
        v2f vsig; vsig[0] = 0.0f; vsig[1] = sigv[s - 1];

        // assemble 4x4 v2f window: own 2x2 from regs + 12 halo b64 reads
        v2f v[4][4];
#pragma unroll
        for (int i = 0; i < 2; ++i)
#pragma unroll
            for (int j = 0; j < 2; ++j)
                v[i + 1][j + 1] = cur[i * 2 + j];
        v[0][0] = rb[rm][cm];  v[0][3] = rb[rm][cp];
        v[3][0] = rb[rp][cm];  v[3][3] = rb[rp][cp];
#pragma unroll
        for (int j = 0; j < 2; ++j) {
            v[0][j + 1] = rb[rm][c0 + j];
            v[3][j + 1] = rb[rp][c0 + j];
            v[j + 1][0] = rb[r0 + j][cm];
            v[j + 1][3] = rb[r0 + j][cp];
        }

        // horizontal differences shared across the 4 points' cross-derivs
        v2f dh[4][2];
#pragma unroll
        for (int i = 0; i < 4; ++i)
#pragma unroll
            for (int j = 0; j < 2; ++j)
                dh[i][j] = v[i][j + 2] - v[i][j];

#pragma unroll
        for (int i = 0; i < 2; ++i)
#pragma unroll
            for (int j = 0; j < 2; ++j) {
                int p = i * 2 + j;
                v2f c = v[i + 1][j + 1];
                v2f sxx = vfma(m2, c, v[i][j + 1] + v[i + 2][j + 1]);  // pk
                v2f syy = vfma(m2, c, v[i + 1][j] + v[i + 1][j + 2]);  // pk
                v2f sxy = qt * (dh[i + 2][j] - dh[i][j]);              // pk

                // t4 = {2*sxy.x + sxx.y, sxx.x}; t5 = {syy.y, 2*sxy.y + syy.x}
                v2f t4 = vfma(c20, vbc(sxy[0]), vswap(sxx));
                v2f t5 = vfma(c02, vbc(sxy[1]), vswap(syy));
                // L = {lux, luy}
                v2f Lv = ca[p] * sxx;
                Lv = vfma(cb[p], syy, Lv);
                Lv = vfma(vbc(a12p66[p]), vswap(sxy), Lv);
                Lv = vfma(vbc(a16[p]), t4, Lv);
                Lv = vfma(vbc(a26[p]), t5, Lv);
                // source on y only: {lux, sig*gs + luy} (exact: 0*gs+lux)
                Lv = vfma(vsig, vbc(gs[p]), Lv);
                // n = fma(2, c, L) - old
                v2f n = vfma(two, c, Lv) - old_[p];
                old_[p] = c;
                cur[p] = n;
            }

        // frame output at global t = t0 + s - 1; t%4==3 <=> s%4==0
        // (fire-and-forget: the step barrier does NOT drain vmcnt)
        if ((s & 3) == 0 && owned) {
            int f = 2 * L + (s >> 2) - 1;
            float* oux = out + (size_t)f * NPT;
            float* ouy = out + (size_t)(NFRAMES + f) * NPT;
#pragma unroll
            for (int p = 0; p < 4; ++p) {
                oux[gidx[p]] = cur[p][0];
                ouy[gidx[p]] = cur[p][1];
            }
        }

        // publish new values; ONE lgkm-only barrier per step (double buffered)
#pragma unroll
        for (int i = 0; i < 2; ++i)
#pragma unroll
            for (int j = 0; j < 2; ++j)
                wb[r0 + i][c0 + j] = cur[i * 2 + j];
        LDS_BARRIER();
    }

    if (owned) {
#pragma unroll
        for (int p = 0; p < 4; ++p) {
            float4 st = make_float4(cur[p][0], cur[p][1], old_[p][0], old_[p][1]);
            outS[gidx[p]] = st;
        }
    }
}

extern "C" void kernel_launch(void* const* d_in, const int* in_sizes, int n_in,
                              void* d_out, int out_size, void* d_ws, size_t ws_size,
                              hipStream_t stream) {
    const float* lc11  = (const float*)d_in[0];
    const float* lc12  = (const float*)d_in[1];
    const float* lc16  = (const float*)d_in[2];
    const float* lc22  = (const float*)d_in[3];
    const float* lc26  = (const float*)d_in[4];
    const float* lc66  = (const float*)d_in[5];
    const float* gauss = (const float*)d_in[6];
    const float* sig   = (const float*)d_in[7];

    float* ws  = (float*)d_ws;
    float* out = (float*)d_out;

    setup_kernel<<<(NPT + 255) / 256, 256, 0, stream>>>(lc11, lc12, lc16, lc22,
                                                        lc26, lc66, gauss, ws);

    float4* set0 = (float4*)(ws + 8 * (size_t)NPT);
    float4* set1 = (float4*)(ws + 12 * (size_t)NPT);

    dim3 grid(NXg / OWN, NYg / OWN);  // 24x24 = 576 blocks, 2-3 per CU
    for (int L = 0; L < NLAUNCH; ++L) {
        float4* iS = (L & 1) ? set1 : set0;
        float4* oS = (L & 1) ? set0 : set1;
        fused_kernel<<<grid, 256, 0, stream>>>(ws, sig, iS, oS, out, L);
    }
}

// Round 4
// 326.796 us; speedup vs baseline: 2.4857x; 1.1350x over previous
//
#include <hip/hip_runtime.h>

// Spatially varying anisotropic 2D elastic wave sim, 384x384, 192 steps.
// Round 12: R8 geometry (best known: OWN=24, HALO=K=12, TS=48, 16 launches,
// 256 blocks = 1/CU, 256 thr, packed v2f LDS + pk stencil math, wide float4
// coeff/state, lgkm-only barrier) with the per-step scratch bug fixed:
//  - FULL UNROLL of the 12-step loop: sigv[s-1] was a runtime-indexed
//    private array inside '#pragma unroll 1' -> allocated in SCRATCH
//    (rule #20), a per-step VMEM load on the Lv critical path, re-issued
//    every step by the barrier's memory clobber. Occupancy-invariant --
//    matches the R10/R11 finding that per-step cost (~1.7us) ignores
//    waves/SIMD. Unrolled, sigv is registers.
//  - skip dead LDS traffic: each thread's 3x3 CENTER cell is never read
//    by any neighbor (halo reads touch boundary cells only) -> publish
//    8/9 cells; final step's publish+barrier are dead -> removed.

typedef float v2f __attribute__((ext_vector_type(2)));

#define NXg 384
#define NYg 384
#define NPT (NXg * NYg)
#define NFRAMES 48

#define OWN 24
#define HALO 12
#define TS 48
#define KSTEPS 12
#define NLAUNCH 16

#define H_   1e-4
#define DT_  5e-9
#define RHO_ 1610.0

#define B11_LO 5e10f
#define B11_HI 2.5e11f
#define B22_LO 5e9f
#define B22_HI 5e10f
#define B12_LO 5e9f
#define B12_HI 5e10f
#define B16_LO 0.0f
#define B16_HI 6e10f
#define B26_LO 0.0f
#define B26_HI 2e10f
#define B66_LO 5e9f
#define B66_HI 3e10f

static __device__ __constant__ float kScale  = (float)(DT_ * DT_ / (H_ * H_) / RHO_);
static __device__ __constant__ float kSrcScl = (float)(DT_ * DT_ / RHO_);

__device__ __forceinline__ float clipf(float v, float lo, float hi) {
    return fminf(fmaxf(v, lo), hi);
}
__device__ __forceinline__ v2f vfma(v2f a, v2f b, v2f c) {
    return __builtin_elementwise_fma(a, b, c);
}
__device__ __forceinline__ v2f vbc(float s) { v2f r; r[0] = s; r[1] = s; return r; }
__device__ __forceinline__ v2f vswap(v2f a) { return __builtin_shufflevector(a, a, 1, 0); }

// barrier that only waits LDS (no vmcnt drain); memory clobber pins ordering
#define LDS_BARRIER() asm volatile("s_waitcnt lgkmcnt(0)\n\ts_barrier" ::: "memory")

// ws float layout:
// [0..4NPT):   C0 = float4{A11, A22, A12p66, A16}  (pre-scaled)
// [4NPT..8NPT):C1 = float4{A26, A66, GS, 0}
// [8NPT..12NPT):  state set0: float4{cur.x, cur.y, old.x, old.y}
// [12NPT..16NPT): state set1

__global__ __launch_bounds__(256)
void setup_kernel(const float* __restrict__ lc11, const float* __restrict__ lc12,
                  const float* __restrict__ lc16, const float* __restrict__ lc22,
                  const float* __restrict__ lc26, const float* __restrict__ lc66,
                  const float* __restrict__ gauss, float* __restrict__ ws) {
    int i = blockIdx.x * blockDim.x + threadIdx.x;
    if (i >= NPT) return;
    float C11 = clipf(expf(lc11[i]), B11_LO, B11_HI);
    float C12 = clipf(expf(lc12[i]), B12_LO, B12_HI);
    float C16 = clipf(expf(lc16[i]), B16_LO, B16_HI);
    float C22 = clipf(expf(lc22[i]), B22_LO, B22_HI);
    float C26 = clipf(expf(lc26[i]), B26_LO, B26_HI);
    float C66 = clipf(expf(lc66[i]), B66_LO, B66_HI);
    float s = kScale;
    float4* C0 = (float4*)ws;
    float4* C1 = (float4*)(ws + 4 * (size_t)NPT);
    C0[i] = make_float4(C11 * s, C22 * s, (C12 + C66) * s, C16 * s);
    C1[i] = make_float4(C26 * s, C66 * s, gauss[i] * kSrcScl, 0.0f);
    float4* s0 = (float4*)(ws + 8 * (size_t)NPT);
    s0[i] = make_float4(0.0f, 0.0f, 0.0f, 0.0f);
}

__global__ __launch_bounds__(256, 1)
void fused_kernel(const float* __restrict__ ws, const float* __restrict__ sig,
                  const float4* __restrict__ inS, float4* __restrict__ outS,
                  float* __restrict__ out, int L) {
    __shared__ v2f sb[2][TS][TS + 1];

    const int tid = threadIdx.x;
    const int tx = tid >> 4;
    const int ty = tid & 15;
    const int r0 = 3 * tx;
    const int c0 = 3 * ty;
    const int gx0 = blockIdx.y * OWN - HALO;
    const int gy0 = blockIdx.x * OWN - HALO;

    const float4* __restrict__ C0 = (const float4*)ws;
    const float4* __restrict__ C1 = (const float4*)(ws + 4 * (size_t)NPT);

    v2f cur[9], old_[9];
    v2f ca[9], cb[9];                       // {A11,A66}, {A66,A22}
    float a12p66[9], a16[9], a26[9], gs[9];
    int gidx[9];

#pragma unroll
    for (int i = 0; i < 3; ++i) {
#pragma unroll
        for (int j = 0; j < 3; ++j) {
            int p = i * 3 + j;
            int gx = gx0 + r0 + i;
            int gy = gy0 + c0 + j;
            bool d = (unsigned)gx < (unsigned)NXg && (unsigned)gy < (unsigned)NYg;
            int g = d ? gx * NYg + gy : 0;
            gidx[p] = g;
            float4 st = d ? inS[g] : make_float4(0, 0, 0, 0);
            v2f c; c[0] = st.x; c[1] = st.y;
            v2f o; o[0] = st.z; o[1] = st.w;
            cur[p] = c; old_[p] = o;
            float4 k0 = d ? C0[g] : make_float4(0, 0, 0, 0);
            float4 k1 = d ? C1[g] : make_float4(0, 0, 0, 0);
            v2f t; t[0] = k0.x; t[1] = k1.y; ca[p] = t;   // {A11, A66}
            v2f u; u[0] = k1.y; u[1] = k0.y; cb[p] = u;   // {A66, A22}
            a12p66[p] = k0.z; a16[p] = k0.w; a26[p] = k1.x; gs[p] = k1.z;
        }
    }

    // preload all step source values; step loop is FULLY UNROLLED below, so
    // sigv is statically indexed -> stays in registers (no scratch).
    const int t0 = L * KSTEPS;
    float sigv[KSTEPS];
#pragma unroll
    for (int k = 0; k < KSTEPS; ++k) sigv[k] = sig[t0 + k];

    // clamped halo coords (trapezoid garbage-tolerance at staging rim)
    const int rm = (r0 > 0) ? r0 - 1 : 0;
    const int rp = (r0 + 3 < TS) ? r0 + 3 : TS - 1;
    const int cm = (c0 > 0) ? c0 - 1 : 0;
    const int cp = (c0 + 3 < TS) ? c0 + 3 : TS - 1;

    const bool owned = (tx >= 4) && (tx < 12) && (ty >= 4) && (ty < 12);

    // publish initial values into buffer 0 (center cell never read -> skip)
#pragma unroll
    for (int i = 0; i < 3; ++i)
#pragma unroll
        for (int j = 0; j < 3; ++j)
            if (!(i == 1 && j == 1))
                sb[0][r0 + i][c0 + j] = cur[i * 3 + j];
    LDS_BARRIER();

    v2f c20; c20[0] = 2.0f; c20[1] = 0.0f;
    v2f c02; c02[0] = 0.0f; c02[1] = 2.0f;
    const v2f m2 = vbc(-2.0f);
    const v2f qt = vbc(0.25f);
    const v2f two = vbc(2.0f);

#pragma unroll
    for (int s = 1; s <= KSTEPS; ++s) {
        const v2f (*rb)[TS + 1] = sb[(s - 1) & 1];
        v2f (*wb)[TS + 1] = sb[s & 1];
        v2f vsig; vsig[0] = 0.0f; vsig[1] = sigv[s - 1];

        // assemble 5x5 v2f window: own 3x3 from regs + 16 halo b64 reads
        v2f v[5][5];
#pragma unroll
        for (int i = 0; i < 3; ++i)
#pragma unroll
            for (int j = 0; j < 3; ++j)
                v[i + 1][j + 1] = cur[i * 3 + j];
        v[0][0] = rb[rm][cm];  v[0][4] = rb[rm][cp];
        v[4][0] = rb[rp][cm];  v[4][4] = rb[rp][cp];
#pragma unroll
        for (int j = 0; j < 3; ++j) {
            v[0][j + 1] = rb[rm][c0 + j];
            v[4][j + 1] = rb[rp][c0 + j];
            v[j + 1][0] = rb[r0 + j][cm];
            v[j + 1][4] = rb[r0 + j][cp];
        }

        // horizontal differences shared across the 9 points' cross-derivs
        v2f dh[5][3];
#pragma unroll
        for (int i = 0; i < 5; ++i)
#pragma unroll
            for (int j = 0; j < 3; ++j)
                dh[i][j] = v[i][j + 2] - v[i][j];

#pragma unroll
        for (int i = 0; i < 3; ++i)
#pragma unroll
            for (int j = 0; j < 3; ++j) {
                int p = i * 3 + j;
                v2f c = v[i + 1][j + 1];
                v2f sxx = vfma(m2, c, v[i][j + 1] + v[i + 2][j + 1]);  // pk
                v2f syy = vfma(m2, c, v[i + 1][j] + v[i + 1][j + 2]);  // pk
                v2f sxy = qt * (dh[i + 2][j] - dh[i][j]);              // pk

                // t4 = {2*sxy.x + sxx.y, sxx.x}; t5 = {syy.y, 2*sxy.y + syy.x}
                v2f t4 = vfma(c20, vbc(sxy[0]), vswap(sxx));
                v2f t5 = vfma(c02, vbc(sxy[1]), vswap(syy));
                // L = {lux, luy}
                v2f Lv = ca[p] * sxx;
                Lv = vfma(cb[p], syy, Lv);
                Lv = vfma(vbc(a12p66[p]), vswap(sxy), Lv);
                Lv = vfma(vbc(a16[p]), t4, Lv);
                Lv = vfma(vbc(a26[p]), t5, Lv);
                // source on y only: {lux, sig*gs + luy} (exact: 0*gs+lux)
                Lv = vfma(vsig, vbc(gs[p]), Lv);
                // n = fma(2, c, L) - old
                v2f n = vfma(two, c, Lv) - old_[p];
                old_[p] = c;
                cur[p] = n;
            }

        // frame output at global t = t0 + s - 1; t%4==3 <=> s%4==0
        // (fire-and-forget: the step barrier does NOT drain vmcnt)
        if ((s & 3) == 0 && owned) {
            int f = 3 * L + (s >> 2) - 1;
            float* oux = out + (size_t)f * NPT;
            float* ouy = out + (size_t)(NFRAMES + f) * NPT;
#pragma unroll
            for (int p = 0; p < 9; ++p) {
                oux[gidx[p]] = cur[p][0];
                ouy[gidx[p]] = cur[p][1];
            }
        }

        // publish new values (boundary cells only; center never read).
        // Final step's publish + barrier are dead -> skipped.
        if (s < KSTEPS) {
#pragma unroll
            for (int i = 0; i < 3; ++i)
#pragma unroll
                for (int j = 0; j < 3; ++j)
                    if (!(i == 1 && j == 1))
                        wb[r0 + i][c0 + j] = cur[i * 3 + j];
            LDS_BARRIER();
        }
    }

    if (owned) {
#pragma unroll
        for (int p = 0; p < 9; ++p) {
            float4 st = make_float4(cur[p][0], cur[p][1], old_[p][0], old_[p][1]);
            outS[gidx[p]] = st;
        }
    }
}

extern "C" void kernel_launch(void* const* d_in, const int* in_sizes, int n_in,
                              void* d_out, int out_size, void* d_ws, size_t ws_size,
                              hipStream_t stream) {
    const float* lc11  = (const float*)d_in[0];
    const float* lc12  = (const float*)d_in[1];
    const float* lc16  = (const float*)d_in[2];
    const float* lc22  = (const float*)d_in[3];
    const float* lc26  = (const float*)d_in[4];
    const float* lc66  = (const float*)d_in[5];
    const float* gauss = (const float*)d_in[6];
    const float* sig   = (const float*)d_in[7];

    float* ws  = (float*)d_ws;
    float* out = (float*)d_out;

    setup_kernel<<<(NPT + 255) / 256, 256, 0, stream>>>(lc11, lc12, lc16, lc22,
                                                        lc26, lc66, gauss, ws);

    float4* set0 = (float4*)(ws + 8 * (size_t)NPT);
    float4* set1 = (float4*)(ws + 12 * (size_t)NPT);

    dim3 grid(NXg / OWN, NYg / OWN);  // 16x16 = 256 blocks, 1 per CU
    for (int L = 0; L < NLAUNCH; ++L) {
        float4* iS = (L & 1) ? set1 : set0;
        float4* oS = (L & 1) ? set0 : set1;
        fused_kernel<<<grid, 256, 0, stream>>>(ws, sig, iS, oS, out, L);
    }
}

// Round 5
// 319.024 us; speedup vs baseline: 2.5462x; 1.0244x over previous
//
#include <hip/hip_runtime.h>

// Spatially varying anisotropic 2D elastic wave sim, 384x384, 192 steps.
// Round 13: R12 (326.8us) + LDS diet via in-wave DPP column exchange.
// Theory: per-step stall (~2600cy) is occupancy-invariant (R11 null) ->
// per-CU shared LDS pipe + write->lgkm->barrier->read roundtrip. Cut LDS:
//  - left/right halo COLUMNS come from lane+-1 (same 16-lane DPP row) via
//    v_mov_dpp row_shr:1/row_shl:1 reading the neighbor's cur registers.
//    bound_ctrl=0 "keep old" == the rim clamp (ty=0: cm=c0 -> own col).
//  - middle row of each thread's 3x3 is then never read from LDS ->
//    publish only rows 0 and 2. LDS per thread-step: 16r+8w -> 10r+6w.
//  - rows rm/rp (cross-wave, tx+-1 may cross the 16-lane row) stay in LDS.
// Everything else identical to R12 (full unroll, reg sigv, lgkm barrier,
// wide float4 coeff/state, fire-and-forget frame stores).

typedef float v2f __attribute__((ext_vector_type(2)));

#define NXg 384
#define NYg 384
#define NPT (NXg * NYg)
#define NFRAMES 48

#define OWN 24
#define HALO 12
#define TS 48
#define KSTEPS 12
#define NLAUNCH 16

#define H_   1e-4
#define DT_  5e-9
#define RHO_ 1610.0

#define B11_LO 5e10f
#define B11_HI 2.5e11f
#define B22_LO 5e9f
#define B22_HI 5e10f
#define B12_LO 5e9f
#define B12_HI 5e10f
#define B16_LO 0.0f
#define B16_HI 6e10f
#define B26_LO 0.0f
#define B26_HI 2e10f
#define B66_LO 5e9f
#define B66_HI 3e10f

#define ROW_SHR1 0x111   // dst[lane] = src[lane-1] within 16-lane row
#define ROW_SHL1 0x101   // dst[lane] = src[lane+1] within 16-lane row

static __device__ __constant__ float kScale  = (float)(DT_ * DT_ / (H_ * H_) / RHO_);
static __device__ __constant__ float kSrcScl = (float)(DT_ * DT_ / RHO_);

__device__ __forceinline__ float clipf(float v, float lo, float hi) {
    return fminf(fmaxf(v, lo), hi);
}
__device__ __forceinline__ v2f vfma(v2f a, v2f b, v2f c) {
    return __builtin_elementwise_fma(a, b, c);
}
__device__ __forceinline__ v2f vbc(float s) { v2f r; r[0] = s; r[1] = s; return r; }
__device__ __forceinline__ v2f vswap(v2f a) { return __builtin_shufflevector(a, a, 1, 0); }

// in-wave halo import: neighbor lane's v2f via 2x v_mov_dpp.
// Invalid lanes (row edge) receive 'oldv' == the rim-clamp value.
template <int CTRL>
__device__ __forceinline__ v2f dpp_shift(v2f oldv, v2f src) {
    union { v2f v; int i[2]; } o, s, r;
    o.v = oldv; s.v = src;
    r.i[0] = __builtin_amdgcn_update_dpp(o.i[0], s.i[0], CTRL, 0xf, 0xf, false);
    r.i[1] = __builtin_amdgcn_update_dpp(o.i[1], s.i[1], CTRL, 0xf, 0xf, false);
    return r.v;
}

// barrier that only waits LDS (no vmcnt drain); memory clobber pins ordering
#define LDS_BARRIER() asm volatile("s_waitcnt lgkmcnt(0)\n\ts_barrier" ::: "memory")

// ws float layout:
// [0..4NPT):   C0 = float4{A11, A22, A12p66, A16}  (pre-scaled)
// [4NPT..8NPT):C1 = float4{A26, A66, GS, 0}
// [8NPT..12NPT):  state set0: float4{cur.x, cur.y, old.x, old.y}
// [12NPT..16NPT): state set1

__global__ __launch_bounds__(256)
void setup_kernel(const float* __restrict__ lc11, const float* __restrict__ lc12,
                  const float* __restrict__ lc16, const float* __restrict__ lc22,
                  const float* __restrict__ lc26, const float* __restrict__ lc66,
                  const float* __restrict__ gauss, float* __restrict__ ws) {
    int i = blockIdx.x * blockDim.x + threadIdx.x;
    if (i >= NPT) return;
    float C11 = clipf(expf(lc11[i]), B11_LO, B11_HI);
    float C12 = clipf(expf(lc12[i]), B12_LO, B12_HI);
    float C16 = clipf(expf(lc16[i]), B16_LO, B16_HI);
    float C22 = clipf(expf(lc22[i]), B22_LO, B22_HI);
    float C26 = clipf(expf(lc26[i]), B26_LO, B26_HI);
    float C66 = clipf(expf(lc66[i]), B66_LO, B66_HI);
    float s = kScale;
    float4* C0 = (float4*)ws;
    float4* C1 = (float4*)(ws + 4 * (size_t)NPT);
    C0[i] = make_float4(C11 * s, C22 * s, (C12 + C66) * s, C16 * s);
    C1[i] = make_float4(C26 * s, C66 * s, gauss[i] * kSrcScl, 0.0f);
    float4* s0 = (float4*)(ws + 8 * (size_t)NPT);
    s0[i] = make_float4(0.0f, 0.0f, 0.0f, 0.0f);
}

__global__ __launch_bounds__(256, 1)
void fused_kernel(const float* __restrict__ ws, const float* __restrict__ sig,
                  const float4* __restrict__ inS, float4* __restrict__ outS,
                  float* __restrict__ out, int L) {
    __shared__ v2f sb[2][TS][TS + 1];

    const int tid = threadIdx.x;
    const int tx = tid >> 4;
    const int ty = tid & 15;
    const int r0 = 3 * tx;
    const int c0 = 3 * ty;
    const int gx0 = blockIdx.y * OWN - HALO;
    const int gy0 = blockIdx.x * OWN - HALO;

    const float4* __restrict__ C0 = (const float4*)ws;
    const float4* __restrict__ C1 = (const float4*)(ws + 4 * (size_t)NPT);

    v2f cur[9], old_[9];
    v2f ca[9], cb[9];                       // {A11,A66}, {A66,A22}
    float a12p66[9], a16[9], a26[9], gs[9];
    int gidx[9];

#pragma unroll
    for (int i = 0; i < 3; ++i) {
#pragma unroll
        for (int j = 0; j < 3; ++j) {
            int p = i * 3 + j;
            int gx = gx0 + r0 + i;
            int gy = gy0 + c0 + j;
            bool d = (unsigned)gx < (unsigned)NXg && (unsigned)gy < (unsigned)NYg;
            int g = d ? gx * NYg + gy : 0;
            gidx[p] = g;
            float4 st = d ? inS[g] : make_float4(0, 0, 0, 0);
            v2f c; c[0] = st.x; c[1] = st.y;
            v2f o; o[0] = st.z; o[1] = st.w;
            cur[p] = c; old_[p] = o;
            float4 k0 = d ? C0[g] : make_float4(0, 0, 0, 0);
            float4 k1 = d ? C1[g] : make_float4(0, 0, 0, 0);
            v2f t; t[0] = k0.x; t[1] = k1.y; ca[p] = t;   // {A11, A66}
            v2f u; u[0] = k1.y; u[1] = k0.y; cb[p] = u;   // {A66, A22}
            a12p66[p] = k0.z; a16[p] = k0.w; a26[p] = k1.x; gs[p] = k1.z;
        }
    }

    // preload all step source values; step loop FULLY UNROLLED -> registers
    const int t0 = L * KSTEPS;
    float sigv[KSTEPS];
#pragma unroll
    for (int k = 0; k < KSTEPS; ++k) sigv[k] = sig[t0 + k];

    // clamped halo coords (trapezoid garbage-tolerance at staging rim)
    const int rm = (r0 > 0) ? r0 - 1 : 0;
    const int rp = (r0 + 3 < TS) ? r0 + 3 : TS - 1;
    const int cm = (c0 > 0) ? c0 - 1 : 0;
    const int cp = (c0 + 3 < TS) ? c0 + 3 : TS - 1;

    const bool owned = (tx >= 4) && (tx < 12) && (ty >= 4) && (ty < 12);

    // publish initial values into buffer 0 -- rows 0 and 2 only (middle row
    // and side columns are served by in-wave DPP, never read from LDS)
#pragma unroll
    for (int j = 0; j < 3; ++j) {
        sb[0][r0 + 0][c0 + j] = cur[0 * 3 + j];
        sb[0][r0 + 2][c0 + j] = cur[2 * 3 + j];
    }
    LDS_BARRIER();

    v2f c20; c20[0] = 2.0f; c20[1] = 0.0f;
    v2f c02; c02[0] = 0.0f; c02[1] = 2.0f;
    const v2f m2 = vbc(-2.0f);
    const v2f qt = vbc(0.25f);
    const v2f two = vbc(2.0f);

#pragma unroll
    for (int s = 1; s <= KSTEPS; ++s) {
        const v2f (*rb)[TS + 1] = sb[(s - 1) & 1];
        v2f (*wb)[TS + 1] = sb[s & 1];
        v2f vsig; vsig[0] = 0.0f; vsig[1] = sigv[s - 1];

        // assemble 5x5 v2f window:
        //  - own 3x3 from regs
        //  - side columns (rows 1..3) from lane+-1 registers via DPP
        //  - top/bottom rows (incl corners) from LDS (10 b64 reads)
        v2f v[5][5];
#pragma unroll
        for (int i = 0; i < 3; ++i)
#pragma unroll
            for (int j = 0; j < 3; ++j)
                v[i + 1][j + 1] = cur[i * 3 + j];
#pragma unroll
        for (int i = 0; i < 3; ++i) {
            v[i + 1][0] = dpp_shift<ROW_SHR1>(cur[i * 3 + 0], cur[i * 3 + 2]);
            v[i + 1][4] = dpp_shift<ROW_SHL1>(cur[i * 3 + 2], cur[i * 3 + 0]);
        }
        v[0][0] = rb[rm][cm];  v[0][4] = rb[rm][cp];
        v[4][0] = rb[rp][cm];  v[4][4] = rb[rp][cp];
#pragma unroll
        for (int j = 0; j < 3; ++j) {
            v[0][j + 1] = rb[rm][c0 + j];
            v[4][j + 1] = rb[rp][c0 + j];
        }

        // horizontal differences shared across the 9 points' cross-derivs
        v2f dh[5][3];
#pragma unroll
        for (int i = 0; i < 5; ++i)
#pragma unroll
            for (int j = 0; j < 3; ++j)
                dh[i][j] = v[i][j + 2] - v[i][j];

#pragma unroll
        for (int i = 0; i < 3; ++i)
#pragma unroll
            for (int j = 0; j < 3; ++j) {
                int p = i * 3 + j;
                v2f c = v[i + 1][j + 1];
                v2f sxx = vfma(m2, c, v[i][j + 1] + v[i + 2][j + 1]);  // pk
                v2f syy = vfma(m2, c, v[i + 1][j] + v[i + 1][j + 2]);  // pk
                v2f sxy = qt * (dh[i + 2][j] - dh[i][j]);              // pk

                // t4 = {2*sxy.x + sxx.y, sxx.x}; t5 = {syy.y, 2*sxy.y + syy.x}
                v2f t4 = vfma(c20, vbc(sxy[0]), vswap(sxx));
                v2f t5 = vfma(c02, vbc(sxy[1]), vswap(syy));
                // L = {lux, luy}
                v2f Lv = ca[p] * sxx;
                Lv = vfma(cb[p], syy, Lv);
                Lv = vfma(vbc(a12p66[p]), vswap(sxy), Lv);
                Lv = vfma(vbc(a16[p]), t4, Lv);
                Lv = vfma(vbc(a26[p]), t5, Lv);
                // source on y only: {lux, sig*gs + luy} (exact: 0*gs+lux)
                Lv = vfma(vsig, vbc(gs[p]), Lv);
                // n = fma(2, c, L) - old
                v2f n = vfma(two, c, Lv) - old_[p];
                old_[p] = c;
                cur[p] = n;
            }

        // frame output at global t = t0 + s - 1; t%4==3 <=> s%4==0
        // (fire-and-forget: the step barrier does NOT drain vmcnt)
        if ((s & 3) == 0 && owned) {
            int f = 3 * L + (s >> 2) - 1;
            float* oux = out + (size_t)f * NPT;
            float* ouy = out + (size_t)(NFRAMES + f) * NPT;
#pragma unroll
            for (int p = 0; p < 9; ++p) {
                oux[gidx[p]] = cur[p][0];
                ouy[gidx[p]] = cur[p][1];
            }
        }

        // publish new values -- rows 0 and 2 only (6 b64 writes).
        // Final step's publish + barrier are dead -> skipped.
        if (s < KSTEPS) {
#pragma unroll
            for (int j = 0; j < 3; ++j) {
                wb[r0 + 0][c0 + j] = cur[0 * 3 + j];
                wb[r0 + 2][c0 + j] = cur[2 * 3 + j];
            }
            LDS_BARRIER();
        }
    }

    if (owned) {
#pragma unroll
        for (int p = 0; p < 9; ++p) {
            float4 st = make_float4(cur[p][0], cur[p][1], old_[p][0], old_[p][1]);
            outS[gidx[p]] = st;
        }
    }
}

extern "C" void kernel_launch(void* const* d_in, const int* in_sizes, int n_in,
                              void* d_out, int out_size, void* d_ws, size_t ws_size,
                              hipStream_t stream) {
    const float* lc11  = (const float*)d_in[0];
    const float* lc12  = (const float*)d_in[1];
    const float* lc16  = (const float*)d_in[2];
    const float* lc22  = (const float*)d_in[3];
    const float* lc26  = (const float*)d_in[4];
    const float* lc66  = (const float*)d_in[5];
    const float* gauss = (const float*)d_in[6];
    const float* sig   = (const float*)d_in[7];

    float* ws  = (float*)d_ws;
    float* out = (float*)d_out;

    setup_kernel<<<(NPT + 255) / 256, 256, 0, stream>>>(lc11, lc12, lc16, lc22,
                                                        lc26, lc66, gauss, ws);

    float4* set0 = (float4*)(ws + 8 * (size_t)NPT);
    float4* set1 = (float4*)(ws + 12 * (size_t)NPT);

    dim3 grid(NXg / OWN, NYg / OWN);  // 16x16 = 256 blocks, 1 per CU
    for (int L = 0; L < NLAUNCH; ++L) {
        float4* iS = (L & 1) ? set1 : set0;
        float4* oS = (L & 1) ? set0 : set1;
        fused_kernel<<<grid, 256, 0, stream>>>(ws, sig, iS, oS, out, L);
    }
}

// Round 6
// 298.691 us; speedup vs baseline: 2.7196x; 1.0681x over previous
//
#include <hip/hip_runtime.h>

// Spatially varying anisotropic 2D elastic wave sim, 384x384, 192 steps.
// Round 14: clean occupancy test. R12/R13 geometry and launch structure
// (OWN=24, HALO=K=12, TS=48, grid 16x16=256 blocks, 16 launches, packed
// v2f LDS + pk stencil, wide float4 coeff/state, lgkm-only barrier, full
// unroll, register sigv) but 576 THREADS/BLOCK (9 waves, 24x24 layout,
// 2x2 cells/thread) instead of 256 threads (4 waves, 3x3 cells):
//  - waves/SIMD 1 -> 2.25 with geometry, barrier count, launch count,
//    and total VALU work per CU unchanged. R11's null occupancy result
//    was confounded (scratch sigv bug + launch_bounds VGPR=85 spills).
//  - 2x2 tile keeps VGPR well under 128 (required for 9 waves/CU).
//  - DPP column exchange dropped (24-wide rows break 16-lane DPP);
//    columns from LDS as in R12 -- known cost ~8us, accepted for
//    variable isolation.
// Null branch pre-registered: dur >= 310us -> occupancy exonerated,
// pivot to fewer-barriers-per-timestep structure.

typedef float v2f __attribute__((ext_vector_type(2)));

#define NXg 384
#define NYg 384
#define NPT (NXg * NYg)
#define NFRAMES 48

#define OWN 24
#define HALO 12
#define TS 48
#define KSTEPS 12
#define NLAUNCH 16
#define NTH 576          // 24x24 threads, 9 waves
#define TROW 24

#define H_   1e-4
#define DT_  5e-9
#define RHO_ 1610.0

#define B11_LO 5e10f
#define B11_HI 2.5e11f
#define B22_LO 5e9f
#define B22_HI 5e10f
#define B12_LO 5e9f
#define B12_HI 5e10f
#define B16_LO 0.0f
#define B16_HI 6e10f
#define B26_LO 0.0f
#define B26_HI 2e10f
#define B66_LO 5e9f
#define B66_HI 3e10f

static __device__ __constant__ float kScale  = (float)(DT_ * DT_ / (H_ * H_) / RHO_);
static __device__ __constant__ float kSrcScl = (float)(DT_ * DT_ / RHO_);

__device__ __forceinline__ float clipf(float v, float lo, float hi) {
    return fminf(fmaxf(v, lo), hi);
}
__device__ __forceinline__ v2f vfma(v2f a, v2f b, v2f c) {
    return __builtin_elementwise_fma(a, b, c);
}
__device__ __forceinline__ v2f vbc(float s) { v2f r; r[0] = s; r[1] = s; return r; }
__device__ __forceinline__ v2f vswap(v2f a) { return __builtin_shufflevector(a, a, 1, 0); }

// barrier that only waits LDS (no vmcnt drain); memory clobber pins ordering
#define LDS_BARRIER() asm volatile("s_waitcnt lgkmcnt(0)\n\ts_barrier" ::: "memory")

// ws float layout:
// [0..4NPT):   C0 = float4{A11, A22, A12p66, A16}  (pre-scaled)
// [4NPT..8NPT):C1 = float4{A26, A66, GS, 0}
// [8NPT..12NPT):  state set0: float4{cur.x, cur.y, old.x, old.y}
// [12NPT..16NPT): state set1

__global__ __launch_bounds__(256)
void setup_kernel(const float* __restrict__ lc11, const float* __restrict__ lc12,
                  const float* __restrict__ lc16, const float* __restrict__ lc22,
                  const float* __restrict__ lc26, const float* __restrict__ lc66,
                  const float* __restrict__ gauss, float* __restrict__ ws) {
    int i = blockIdx.x * blockDim.x + threadIdx.x;
    if (i >= NPT) return;
    float C11 = clipf(expf(lc11[i]), B11_LO, B11_HI);
    float C12 = clipf(expf(lc12[i]), B12_LO, B12_HI);
    float C16 = clipf(expf(lc16[i]), B16_LO, B16_HI);
    float C22 = clipf(expf(lc22[i]), B22_LO, B22_HI);
    float C26 = clipf(expf(lc26[i]), B26_LO, B26_HI);
    float C66 = clipf(expf(lc66[i]), B66_LO, B66_HI);
    float s = kScale;
    float4* C0 = (float4*)ws;
    float4* C1 = (float4*)(ws + 4 * (size_t)NPT);
    C0[i] = make_float4(C11 * s, C22 * s, (C12 + C66) * s, C16 * s);
    C1[i] = make_float4(C26 * s, C66 * s, gauss[i] * kSrcScl, 0.0f);
    float4* s0 = (float4*)(ws + 8 * (size_t)NPT);
    s0[i] = make_float4(0.0f, 0.0f, 0.0f, 0.0f);
}

__global__ __launch_bounds__(NTH)
void fused_kernel(const float* __restrict__ ws, const float* __restrict__ sig,
                  const float4* __restrict__ inS, float4* __restrict__ outS,
                  float* __restrict__ out, int L) {
    __shared__ v2f sb[2][TS][TS + 1];

    const int tid = threadIdx.x;
    const int tx = tid / TROW;
    const int ty = tid % TROW;
    const int r0 = 2 * tx;
    const int c0 = 2 * ty;
    const int gx0 = blockIdx.y * OWN - HALO;
    const int gy0 = blockIdx.x * OWN - HALO;

    const float4* __restrict__ C0 = (const float4*)ws;
    const float4* __restrict__ C1 = (const float4*)(ws + 4 * (size_t)NPT);

    v2f cur[4], old_[4];
    v2f ca[4], cb[4];                       // {A11,A66}, {A66,A22}
    float a12p66[4], a16[4], a26[4], gs[4];
    int gidx[4];

#pragma unroll
    for (int i = 0; i < 2; ++i) {
#pragma unroll
        for (int j = 0; j < 2; ++j) {
            int p = i * 2 + j;
            int gx = gx0 + r0 + i;
            int gy = gy0 + c0 + j;
            bool d = (unsigned)gx < (unsigned)NXg && (unsigned)gy < (unsigned)NYg;
            int g = d ? gx * NYg + gy : 0;
            gidx[p] = g;
            float4 st = d ? inS[g] : make_float4(0, 0, 0, 0);
            v2f c; c[0] = st.x; c[1] = st.y;
            v2f o; o[0] = st.z; o[1] = st.w;
            cur[p] = c; old_[p] = o;
            float4 k0 = d ? C0[g] : make_float4(0, 0, 0, 0);
            float4 k1 = d ? C1[g] : make_float4(0, 0, 0, 0);
            v2f t; t[0] = k0.x; t[1] = k1.y; ca[p] = t;   // {A11, A66}
            v2f u; u[0] = k1.y; u[1] = k0.y; cb[p] = u;   // {A66, A22}
            a12p66[p] = k0.z; a16[p] = k0.w; a26[p] = k1.x; gs[p] = k1.z;
        }
    }

    // preload all step source values; step loop FULLY UNROLLED -> registers
    const int t0 = L * KSTEPS;
    float sigv[KSTEPS];
#pragma unroll
    for (int k = 0; k < KSTEPS; ++k) sigv[k] = sig[t0 + k];

    // clamped halo coords (trapezoid garbage-tolerance at staging rim)
    const int rm = (r0 > 0) ? r0 - 1 : 0;
    const int rp = (r0 + 2 < TS) ? r0 + 2 : TS - 1;
    const int cm = (c0 > 0) ? c0 - 1 : 0;
    const int cp = (c0 + 2 < TS) ? c0 + 2 : TS - 1;

    // owned core: cells [12,36) -> threads [6,18) in both axes
    const bool owned = (tx >= 6) && (tx < 18) && (ty >= 6) && (ty < 18);

    // publish initial values into buffer 0 (all 4 cells are 2x2 boundary)
#pragma unroll
    for (int i = 0; i < 2; ++i)
#pragma unroll
        for (int j = 0; j < 2; ++j)
            sb[0][r0 + i][c0 + j] = cur[i * 2 + j];
    LDS_BARRIER();

    v2f c20; c20[0] = 2.0f; c20[1] = 0.0f;
    v2f c02; c02[0] = 0.0f; c02[1] = 2.0f;
    const v2f m2 = vbc(-2.0f);
    const v2f qt = vbc(0.25f);
    const v2f two = vbc(2.0f);

#pragma unroll
    for (int s = 1; s <= KSTEPS; ++s) {
        const v2f (*rb)[TS + 1] = sb[(s - 1) & 1];
        v2f (*wb)[TS + 1] = sb[s & 1];
        v2f vsig; vsig[0] = 0.0f; vsig[1] = sigv[s - 1];

        // assemble 4x4 v2f window: own 2x2 from regs + 12 halo b64 reads
        v2f v[4][4];
#pragma unroll
        for (int i = 0; i < 2; ++i)
#pragma unroll
            for (int j = 0; j < 2; ++j)
                v[i + 1][j + 1] = cur[i * 2 + j];
        v[0][0] = rb[rm][cm];  v[0][3] = rb[rm][cp];
        v[3][0] = rb[rp][cm];  v[3][3] = rb[rp][cp];
#pragma unroll
        for (int j = 0; j < 2; ++j) {
            v[0][j + 1] = rb[rm][c0 + j];
            v[3][j + 1] = rb[rp][c0 + j];
            v[j + 1][0] = rb[r0 + j][cm];
            v[j + 1][3] = rb[r0 + j][cp];
        }

        // horizontal differences shared across the 4 points' cross-derivs
        v2f dh[4][2];
#pragma unroll
        for (int i = 0; i < 4; ++i)
#pragma unroll
            for (int j = 0; j < 2; ++j)
                dh[i][j] = v[i][j + 2] - v[i][j];

#pragma unroll
        for (int i = 0; i < 2; ++i)
#pragma unroll
            for (int j = 0; j < 2; ++j) {
                int p = i * 2 + j;
                v2f c = v[i + 1][j + 1];
                v2f sxx = vfma(m2, c, v[i][j + 1] + v[i + 2][j + 1]);  // pk
                v2f syy = vfma(m2, c, v[i + 1][j] + v[i + 1][j + 2]);  // pk
                v2f sxy = qt * (dh[i + 2][j] - dh[i][j]);              // pk

                // t4 = {2*sxy.x + sxx.y, sxx.x}; t5 = {syy.y, 2*sxy.y + syy.x}
                v2f t4 = vfma(c20, vbc(sxy[0]), vswap(sxx));
                v2f t5 = vfma(c02, vbc(sxy[1]), vswap(syy));
                // L = {lux, luy}
                v2f Lv = ca[p] * sxx;
                Lv = vfma(cb[p], syy, Lv);
                Lv = vfma(vbc(a12p66[p]), vswap(sxy), Lv);
                Lv = vfma(vbc(a16[p]), t4, Lv);
                Lv = vfma(vbc(a26[p]), t5, Lv);
                // source on y only: {lux, sig*gs + luy} (exact: 0*gs+lux)
                Lv = vfma(vsig, vbc(gs[p]), Lv);
                // n = fma(2, c, L) - old
                v2f n = vfma(two, c, Lv) - old_[p];
                old_[p] = c;
                cur[p] = n;
            }

        // frame output at global t = t0 + s - 1; t%4==3 <=> s%4==0
        // (fire-and-forget: the step barrier does NOT drain vmcnt)
        if ((s & 3) == 0 && owned) {
            int f = 3 * L + (s >> 2) - 1;
            float* oux = out + (size_t)f * NPT;
            float* ouy = out + (size_t)(NFRAMES + f) * NPT;
#pragma unroll
            for (int p = 0; p < 4; ++p) {
                oux[gidx[p]] = cur[p][0];
                ouy[gidx[p]] = cur[p][1];
            }
        }

        // publish new values; final step's publish + barrier are dead
        if (s < KSTEPS) {
#pragma unroll
            for (int i = 0; i < 2; ++i)
#pragma unroll
                for (int j = 0; j < 2; ++j)
                    wb[r0 + i][c0 + j] = cur[i * 2 + j];
            LDS_BARRIER();
        }
    }

    if (owned) {
#pragma unroll
        for (int p = 0; p < 4; ++p) {
            float4 st = make_float4(cur[p][0], cur[p][1], old_[p][0], old_[p][1]);
            outS[gidx[p]] = st;
        }
    }
}

extern "C" void kernel_launch(void* const* d_in, const int* in_sizes, int n_in,
                              void* d_out, int out_size, void* d_ws, size_t ws_size,
                              hipStream_t stream) {
    const float* lc11  = (const float*)d_in[0];
    const float* lc12  = (const float*)d_in[1];
    const float* lc16  = (const float*)d_in[2];
    const float* lc22  = (const float*)d_in[3];
    const float* lc26  = (const float*)d_in[4];
    const float* lc66  = (const float*)d_in[5];
    const float* gauss = (const float*)d_in[6];
    const float* sig   = (const float*)d_in[7];

    float* ws  = (float*)d_ws;
    float* out = (float*)d_out;

    setup_kernel<<<(NPT + 255) / 256, 256, 0, stream>>>(lc11, lc12, lc16, lc22,
                                                        lc26, lc66, gauss, ws);

    float4* set0 = (float4*)(ws + 8 * (size_t)NPT);
    float4* set1 = (float4*)(ws + 12 * (size_t)NPT);

    dim3 grid(NXg / OWN, NYg / OWN);  // 16x16 = 256 blocks, 1 per CU, 9 waves
    for (int L = 0; L < NLAUNCH; ++L) {
        float4* iS = (L & 1) ? set1 : set0;
        float4* oS = (L & 1) ? set0 : set1;
        fused_kernel<<<grid, NTH, 0, stream>>>(ws, sig, iS, oS, out, L);
    }
}

// Round 7
// 293.406 us; speedup vs baseline: 2.7685x; 1.0180x over previous
//
#include <hip/hip_runtime.h>

// Spatially varying anisotropic 2D elastic wave sim, 384x384, 192 steps.
// Round 15: T48 geometry — same tile/launch structure as R12-R14 (OWN=24,
// HALO=K=12, TS=48, grid 16x16=256 blocks, 16 launches, packed v2f + pk
// math, wide float4 coeff/state, lgkm-only barrier, full unroll, register
// sigv) but 768 THREADS (16 wide x 48 tall, 12 waves = 3 waves/SIMD) with
// 3x1 cells/thread:
//  - occupancy 2.25 -> 3 waves/SIMD (R13->R14 showed waves/SIMD is the
//    live lever: per-step 1.67us@1 -> 1.34us@2.25)
//  - DPP column exchange restored (16-lane-aligned thread rows, R13
//    proven): side cols + all 4 window corners via v_mov_dpp of regs
//  - single cell-row per thread: LDS/step = 6 b64 reads + 3 b64 writes
//    (144 -> 108 wave-ops/block-step), no middle-row special case
//  - VGPR ~140 < 170 cap for 3 waves/SIMD (launch_bounds(768))

typedef float v2f __attribute__((ext_vector_type(2)));

#define NXg 384
#define NYg 384
#define NPT (NXg * NYg)
#define NFRAMES 48

#define OWN 24
#define HALO 12
#define TS 48
#define KSTEPS 12
#define NLAUNCH 16
#define NTH 768          // 16 wide x 48 tall threads, 12 waves
#define TROW 16

#define H_   1e-4
#define DT_  5e-9
#define RHO_ 1610.0

#define B11_LO 5e10f
#define B11_HI 2.5e11f
#define B22_LO 5e9f
#define B22_HI 5e10f
#define B12_LO 5e9f
#define B12_HI 5e10f
#define B16_LO 0.0f
#define B16_HI 6e10f
#define B26_LO 0.0f
#define B26_HI 2e10f
#define B66_LO 5e9f
#define B66_HI 3e10f

#define ROW_SHR1 0x111   // dst[lane] = src[lane-1] within 16-lane row
#define ROW_SHL1 0x101   // dst[lane] = src[lane+1] within 16-lane row

static __device__ __constant__ float kScale  = (float)(DT_ * DT_ / (H_ * H_) / RHO_);
static __device__ __constant__ float kSrcScl = (float)(DT_ * DT_ / RHO_);

__device__ __forceinline__ float clipf(float v, float lo, float hi) {
    return fminf(fmaxf(v, lo), hi);
}
__device__ __forceinline__ v2f vfma(v2f a, v2f b, v2f c) {
    return __builtin_elementwise_fma(a, b, c);
}
__device__ __forceinline__ v2f vbc(float s) { v2f r; r[0] = s; r[1] = s; return r; }
__device__ __forceinline__ v2f vswap(v2f a) { return __builtin_shufflevector(a, a, 1, 0); }

// in-wave halo import: neighbor lane's v2f via 2x v_mov_dpp.
// Invalid lanes (16-lane-row edge) receive 'oldv' == the rim-clamp value.
template <int CTRL>
__device__ __forceinline__ v2f dpp_shift(v2f oldv, v2f src) {
    union { v2f v; int i[2]; } o, s, r;
    o.v = oldv; s.v = src;
    r.i[0] = __builtin_amdgcn_update_dpp(o.i[0], s.i[0], CTRL, 0xf, 0xf, false);
    r.i[1] = __builtin_amdgcn_update_dpp(o.i[1], s.i[1], CTRL, 0xf, 0xf, false);
    return r.v;
}

// barrier that only waits LDS (no vmcnt drain); memory clobber pins ordering
#define LDS_BARRIER() asm volatile("s_waitcnt lgkmcnt(0)\n\ts_barrier" ::: "memory")

// ws float layout:
// [0..4NPT):   C0 = float4{A11, A22, A12p66, A16}  (pre-scaled)
// [4NPT..8NPT):C1 = float4{A26, A66, GS, 0}
// [8NPT..12NPT):  state set0: float4{cur.x, cur.y, old.x, old.y}
// [12NPT..16NPT): state set1

__global__ __launch_bounds__(256)
void setup_kernel(const float* __restrict__ lc11, const float* __restrict__ lc12,
                  const float* __restrict__ lc16, const float* __restrict__ lc22,
                  const float* __restrict__ lc26, const float* __restrict__ lc66,
                  const float* __restrict__ gauss, float* __restrict__ ws) {
    int i = blockIdx.x * blockDim.x + threadIdx.x;
    if (i >= NPT) return;
    float C11 = clipf(expf(lc11[i]), B11_LO, B11_HI);
    float C12 = clipf(expf(lc12[i]), B12_LO, B12_HI);
    float C16 = clipf(expf(lc16[i]), B16_LO, B16_HI);
    float C22 = clipf(expf(lc22[i]), B22_LO, B22_HI);
    float C26 = clipf(expf(lc26[i]), B26_LO, B26_HI);
    float C66 = clipf(expf(lc66[i]), B66_LO, B66_HI);
    float s = kScale;
    float4* C0 = (float4*)ws;
    float4* C1 = (float4*)(ws + 4 * (size_t)NPT);
    C0[i] = make_float4(C11 * s, C22 * s, (C12 + C66) * s, C16 * s);
    C1[i] = make_float4(C26 * s, C66 * s, gauss[i] * kSrcScl, 0.0f);
    float4* s0 = (float4*)(ws + 8 * (size_t)NPT);
    s0[i] = make_float4(0.0f, 0.0f, 0.0f, 0.0f);
}

__global__ __launch_bounds__(NTH)
void fused_kernel(const float* __restrict__ ws, const float* __restrict__ sig,
                  const float4* __restrict__ inS, float4* __restrict__ outS,
                  float* __restrict__ out, int L) {
    __shared__ v2f sb[2][TS][TS + 1];

    const int tid = threadIdx.x;
    const int tx = tid >> 4;          // 0..47 cell row
    const int ty = tid & 15;          // 0..15, 3 cells wide each
    const int r0 = tx;
    const int c0 = 3 * ty;
    const int gx0 = blockIdx.y * OWN - HALO;
    const int gy0 = blockIdx.x * OWN - HALO;

    const float4* __restrict__ C0 = (const float4*)ws;
    const float4* __restrict__ C1 = (const float4*)(ws + 4 * (size_t)NPT);

    v2f cur[3], old_[3];
    v2f ca[3], cb[3];                       // {A11,A66}, {A66,A22}
    float a12p66[3], a16[3], a26[3], gs[3];
    int gidx[3];

#pragma unroll
    for (int j = 0; j < 3; ++j) {
        int gx = gx0 + r0;
        int gy = gy0 + c0 + j;
        bool d = (unsigned)gx < (unsigned)NXg && (unsigned)gy < (unsigned)NYg;
        int g = d ? gx * NYg + gy : 0;
        gidx[j] = g;
        float4 st = d ? inS[g] : make_float4(0, 0, 0, 0);
        v2f c; c[0] = st.x; c[1] = st.y;
        v2f o; o[0] = st.z; o[1] = st.w;
        cur[j] = c; old_[j] = o;
        float4 k0 = d ? C0[g] : make_float4(0, 0, 0, 0);
        float4 k1 = d ? C1[g] : make_float4(0, 0, 0, 0);
        v2f t; t[0] = k0.x; t[1] = k1.y; ca[j] = t;   // {A11, A66}
        v2f u; u[0] = k1.y; u[1] = k0.y; cb[j] = u;   // {A66, A22}
        a12p66[j] = k0.z; a16[j] = k0.w; a26[j] = k1.x; gs[j] = k1.z;
    }

    // preload all step source values; step loop FULLY UNROLLED -> registers
    const int t0 = L * KSTEPS;
    float sigv[KSTEPS];
#pragma unroll
    for (int k = 0; k < KSTEPS; ++k) sigv[k] = sig[t0 + k];

    // clamped vertical halo rows (trapezoid garbage-tolerance at rim)
    const int rm = (r0 > 0) ? r0 - 1 : 0;
    const int rp = (r0 + 1 < TS) ? r0 + 1 : TS - 1;

    // owned core: rows [12,36) -> tx in [12,36); cols [12,36) -> ty in [4,12)
    const bool owned = (tx >= 12) && (tx < 36) && (ty >= 4) && (ty < 12);

    // publish initial values into buffer 0
#pragma unroll
    for (int j = 0; j < 3; ++j)
        sb[0][r0][c0 + j] = cur[j];
    LDS_BARRIER();

    v2f c20; c20[0] = 2.0f; c20[1] = 0.0f;
    v2f c02; c02[0] = 0.0f; c02[1] = 2.0f;
    const v2f m2 = vbc(-2.0f);
    const v2f qt = vbc(0.25f);
    const v2f two = vbc(2.0f);

#pragma unroll
    for (int s = 1; s <= KSTEPS; ++s) {
        const v2f (*rb)[TS + 1] = sb[(s - 1) & 1];
        v2f (*wb)[TS + 1] = sb[s & 1];
        v2f vsig; vsig[0] = 0.0f; vsig[1] = sigv[s - 1];

        // 3x5 window: own row + DPP side cols; rows +-1 from LDS (6 b64)
        // with their side cols via DPP of the loaded values.
        v2f vm[5], vc[5], vp[5];
        vc[1] = cur[0]; vc[2] = cur[1]; vc[3] = cur[2];
        vc[0] = dpp_shift<ROW_SHR1>(cur[0], cur[2]);
        vc[4] = dpp_shift<ROW_SHL1>(cur[2], cur[0]);
        {
            v2f a0 = rb[rm][c0], a1 = rb[rm][c0 + 1], a2 = rb[rm][c0 + 2];
            vm[1] = a0; vm[2] = a1; vm[3] = a2;
            vm[0] = dpp_shift<ROW_SHR1>(a0, a2);
            vm[4] = dpp_shift<ROW_SHL1>(a2, a0);
        }
        {
            v2f b0 = rb[rp][c0], b1 = rb[rp][c0 + 1], b2 = rb[rp][c0 + 2];
            vp[1] = b0; vp[2] = b1; vp[3] = b2;
            vp[0] = dpp_shift<ROW_SHR1>(b0, b2);
            vp[4] = dpp_shift<ROW_SHL1>(b2, b0);
        }

        // horizontal differences for cross-derivs (rows rm, rp only)
        v2f dhm[3], dhp[3];
#pragma unroll
        for (int j = 0; j < 3; ++j) {
            dhm[j] = vm[j + 2] - vm[j];
            dhp[j] = vp[j + 2] - vp[j];
        }

#pragma unroll
        for (int j = 0; j < 3; ++j) {
            v2f c = vc[j + 1];
            v2f sxx = vfma(m2, c, vm[j + 1] + vp[j + 1]);  // pk
            v2f syy = vfma(m2, c, vc[j] + vc[j + 2]);      // pk
            v2f sxy = qt * (dhp[j] - dhm[j]);              // pk

            // t4 = {2*sxy.x + sxx.y, sxx.x}; t5 = {syy.y, 2*sxy.y + syy.x}
            v2f t4 = vfma(c20, vbc(sxy[0]), vswap(sxx));
            v2f t5 = vfma(c02, vbc(sxy[1]), vswap(syy));
            // L = {lux, luy}
            v2f Lv = ca[j] * sxx;
            Lv = vfma(cb[j], syy, Lv);
            Lv = vfma(vbc(a12p66[j]), vswap(sxy), Lv);
            Lv = vfma(vbc(a16[j]), t4, Lv);
            Lv = vfma(vbc(a26[j]), t5, Lv);
            // source on y only: {lux, sig*gs + luy} (exact: 0*gs+lux)
            Lv = vfma(vsig, vbc(gs[j]), Lv);
            // n = fma(2, c, L) - old
            v2f n = vfma(two, c, Lv) - old_[j];
            old_[j] = c;
            cur[j] = n;
        }

        // frame output at global t = t0 + s - 1; t%4==3 <=> s%4==0
        // (fire-and-forget: the step barrier does NOT drain vmcnt)
        if ((s & 3) == 0 && owned) {
            int f = 3 * L + (s >> 2) - 1;
            float* oux = out + (size_t)f * NPT;
            float* ouy = out + (size_t)(NFRAMES + f) * NPT;
#pragma unroll
            for (int j = 0; j < 3; ++j) {
                oux[gidx[j]] = cur[j][0];
                ouy[gidx[j]] = cur[j][1];
            }
        }

        // publish new values; final step's publish + barrier are dead
        if (s < KSTEPS) {
#pragma unroll
            for (int j = 0; j < 3; ++j)
                wb[r0][c0 + j] = cur[j];
            LDS_BARRIER();
        }
    }

    if (owned) {
#pragma unroll
        for (int j = 0; j < 3; ++j) {
            float4 st = make_float4(cur[j][0], cur[j][1], old_[j][0], old_[j][1]);
            outS[gidx[j]] = st;
        }
    }
}

extern "C" void kernel_launch(void* const* d_in, const int* in_sizes, int n_in,
                              void* d_out, int out_size, void* d_ws, size_t ws_size,
                              hipStream_t stream) {
    const float* lc11  = (const float*)d_in[0];
    const float* lc12  = (const float*)d_in[1];
    const float* lc16  = (const float*)d_in[2];
    const float* lc22  = (const float*)d_in[3];
    const float* lc26  = (const float*)d_in[4];
    const float* lc66  = (const float*)d_in[5];
    const float* gauss = (const float*)d_in[6];
    const float* sig   = (const float*)d_in[7];

    float* ws  = (float*)d_ws;
    float* out = (float*)d_out;

    setup_kernel<<<(NPT + 255) / 256, 256, 0, stream>>>(lc11, lc12, lc16, lc22,
                                                        lc26, lc66, gauss, ws);

    float4* set0 = (float4*)(ws + 8 * (size_t)NPT);
    float4* set1 = (float4*)(ws + 12 * (size_t)NPT);

    dim3 grid(NXg / OWN, NYg / OWN);  // 16x16 = 256 blocks, 1 per CU, 12 waves
    for (int L = 0; L < NLAUNCH; ++L) {
        float4* iS = (L & 1) ? set1 : set0;
        float4* oS = (L & 1) ? set0 : set1;
        fused_kernel<<<grid, NTH, 0, stream>>>(ws, sig, iS, oS, out, L);
    }
}